// Round 10
// baseline (984.575 us; speedup 1.0000x reference)
//
#include <hip/hip_runtime.h>

// AF-LSTM on MI355X. Sizes fixed: V=32000, D=H=512, B=64, T=256, A=4, 4H=2048.
// All float tensors f32; x,s int32; d_out f32 [64,512].
// R17 (passed, 968us): tail+prep fusion. LSTM 490us (64 CUs @6% occ); budget
// closes: G1 ~70-100, tail ~50-80, G2-G4 ~60-80, gaps ~30-60. Largest serial
// item = G1, and the LSTM leaves 3/4 of the chip idle for 490us.
// R18: fuse G1 INTO the persistent kernel (blocks 0-63 LSTM unchanged incl.
// bid&7 clique->XCD mapping; blocks 64..2111 = G1 tiles, 8 waves x 64x32).
// LSTM self-paces on Zx with the SAME sentinel protocol as Hs: Zx pre-filled
// 0xFFFFFFFF in prep; G1 epilogue publishes FULL DWORDS (shfl_xor bf16-pair
// packing, relaxed-agent atomic stores -- two 16b stores would create a
// half-dword race vs the dword poll); LSTM's Zx read = proven grouped poll
// (+s_sleep(2): spins only during ramp). G1 tiles in t-MAJOR order so all
// batches' t<128 tiles land first; later tiles finish under the running
// recurrence (128 steps ~ 245us >> G1 tail). No deps on LSTM -> no deadlock;
// blocks 0-63 dispatch first -> cliques co-resident.
// G2/G3/G4 (gemm_bt), tail_kernel unchanged. prep gains the Zx fill region.

typedef __bf16 bf16x8 __attribute__((ext_vector_type(8)));
typedef float f32x4 __attribute__((ext_vector_type(4)));

#define B_ 64
#define T_ 256
#define D_ 512
#define H4 2048
#define SENT 0xFFFFFFFFu

__device__ __forceinline__ unsigned short f2bf(float f) {
    unsigned u = __float_as_uint(f);
    u += 0x7fffu + ((u >> 16) & 1u);   // round-to-nearest-even
    return (unsigned short)(u >> 16);
}
__device__ __forceinline__ float bf2f(unsigned short x) {
    return __uint_as_float(((unsigned)x) << 16);
}
__device__ __forceinline__ float bf2f_lo(unsigned u) { return __uint_as_float(u << 16); }
__device__ __forceinline__ float bf2f_hi(unsigned u) { return __uint_as_float(u & 0xffff0000u); }

__device__ __forceinline__ float frcp(float x) { return __builtin_amdgcn_rcpf(x); }
__device__ __forceinline__ float fast_sigmoid(float x) {
    return frcp(1.f + __expf(-x));
}
__device__ __forceinline__ float fast_tanh(float x) {
    return 1.f - 2.f * frcp(1.f + __expf(2.f * x));
}
__device__ __forceinline__ unsigned ald(const unsigned* p) {
    return __hip_atomic_load(p, __ATOMIC_RELAXED, __HIP_MEMORY_SCOPE_AGENT);
}

// ---------------------------------------------------------------------------
// prep_kernel: region-dispatch by blockIdx (256-thread blocks):
//   [0,2048)       : Hs sentinel fill (16 MiB of 0xFF)
//   [2048,3584)    : Wcat = bf16[W_ih | w_y | w_t]
//   [3584,7680)    : Ebf = bf16(embed[x])
//   [7680,7682)    : aspect normalization
//   [7682,15874)   : Zx sentinel fill (64 MiB of 0xFF)
// ---------------------------------------------------------------------------
__global__ __launch_bounds__(256)
void prep_kernel(const int* __restrict__ x,
                 const int* __restrict__ s,
                 const float* __restrict__ embed,
                 const float* __restrict__ Wih,
                 const float* __restrict__ wy,
                 const float* __restrict__ wt,
                 unsigned short* __restrict__ Wcat,
                 unsigned short* __restrict__ Ebf,
                 uint4* __restrict__ Hs4,
                 uint4* __restrict__ Zx4,
                 float* __restrict__ s_norm,
                 int use_ebf)
{
    __shared__ int sidx[256];
    const int bid = blockIdx.x;
    const int tid = threadIdx.x;

    if (bid < 2048) {
        const int i = (bid * 256 + tid) * 2;
        uint4 v = {SENT, SENT, SENT, SENT};
        Hs4[i] = v;
        Hs4[i + 1] = v;
    } else if (bid < 3584) {
        const int i = ((bid - 2048) * 256 + tid) * 4;
        const float* src; int off;
        if (i < 1048576)      { src = Wih; off = 0; }
        else if (i < 1310720) { src = wy;  off = 1048576; }
        else                  { src = wt;  off = 1310720; }
        float4 v = *(const float4*)(src + (i - off));
        unsigned short o[4] __attribute__((aligned(8)));
        o[0] = f2bf(v.x); o[1] = f2bf(v.y); o[2] = f2bf(v.z); o[3] = f2bf(v.w);
        *(unsigned long long*)(Wcat + i) = *(const unsigned long long*)o;
    } else if (bid < 7680) {
        if (!use_ebf) return;
        const long i = ((long)(bid - 3584) * 256 + tid) * 8;
        const int row = (int)(i >> 9);
        const int col = (int)(i & 511);
        const float* src = embed + (long)x[row] * 512 + col;
        float4 u0 = *(const float4*)(src);
        float4 u1 = *(const float4*)(src + 4);
        unsigned short o[8] __attribute__((aligned(16)));
        o[0] = f2bf(u0.x); o[1] = f2bf(u0.y); o[2] = f2bf(u0.z); o[3] = f2bf(u0.w);
        o[4] = f2bf(u1.x); o[5] = f2bf(u1.y); o[6] = f2bf(u1.z); o[7] = f2bf(u1.w);
        *(uint4*)(Ebf + i) = *(const uint4*)o;
    } else if (bid < 7682) {
        const int d = (bid - 7680) * 256 + tid;
        sidx[tid] = s[tid];
        __syncthreads();
        float sum = 0.f, sq = 0.f;
        for (int i = 0; i < 256; i++) {
            float v = embed[(long)sidx[i] * D_ + d];
            sum += v; sq += v * v;
        }
        float mu = sum * (1.f / 256.f);
        float var = sq * (1.f / 256.f) - mu * mu;
        float rstd = rsqrtf(var + 1e-5f);
        for (int b = 0; b < 64; b++) {
            float acc = 0.f;
            #pragma unroll
            for (int a = 0; a < 4; a++) {
                acc += embed[(long)sidx[b * 4 + a] * D_ + d] - mu;
            }
            s_norm[b * D_ + d] = acc * rstd;
        }
    } else {
        const long i = ((long)(bid - 7682) * 256 + tid) * 2;
        uint4 v = {SENT, SENT, SENT, SENT};
        Zx4[i] = v;
        Zx4[i + 1] = v;
    }
}

// ---------------------------------------------------------------------------
// C = A @ B^T GEMM, bf16 MFMA 16x16x32. 128x128 tile, 4 waves. (unchanged;
// used by G2/G3/G4 only -- G1 now lives inside lstm_g1.)
// ---------------------------------------------------------------------------
__global__ __launch_bounds__(256)
void gemm_bt(const void* __restrict__ Abase, int a_f32,
             const int* __restrict__ gather_idx,
             const unsigned short* __restrict__ Bmat_h,
             const float* __restrict__ circ_src,
             const float* __restrict__ bias,
             unsigned short* __restrict__ outb,
             float* __restrict__ outf,
             int N, int K,
             long A_bstride, long out_bstride,
             int act)
{
    __shared__ __align__(16) unsigned short Asm[128 * 40];
    __shared__ __align__(16) unsigned short Bsm[128 * 40];

    const int bz = blockIdx.z;
    const int tile_n = blockIdx.x * 128;
    const int tile_m = blockIdx.y * 128;
    const int tid = threadIdx.x;
    const int lane = tid & 63;
    const int w = tid >> 6;
    const int wm = (w >> 1) * 64;
    const int wn = (w & 1) * 64;

    const int srow = tid >> 1;
    const int skc = (tid & 1) * 16;

    const float* arow_f = nullptr;
    const unsigned short* arow_h = nullptr;
    if (a_f32) {
        const float* Af = (const float*)Abase;
        if (gather_idx) arow_f = Af + (long)gather_idx[tile_m + srow] * K;
        else            arow_f = Af + (long)bz * A_bstride + (long)(tile_m + srow) * K;
    } else {
        arow_h = (const unsigned short*)Abase + (long)bz * A_bstride + (long)(tile_m + srow) * K;
    }
    const unsigned short* brow_h = nullptr;
    const float* csrc = nullptr;
    if (circ_src) csrc = circ_src + bz * 512;
    else brow_h = Bmat_h + (long)(tile_n + srow) * K;

    f32x4 zero4 = {0.f, 0.f, 0.f, 0.f};
    f32x4 acc[4][4];
    #pragma unroll
    for (int mi = 0; mi < 4; mi++)
        #pragma unroll
        for (int ni = 0; ni < 4; ni++) acc[mi][ni] = zero4;

    const int fr = lane & 15;
    const int fq = (lane >> 4) * 8;

    for (int kc = 0; kc < K; kc += 32) {
        __syncthreads();
        if (a_f32) {
            float4 u0 = *(const float4*)(arow_f + kc + skc);
            float4 u1 = *(const float4*)(arow_f + kc + skc + 4);
            float4 u2 = *(const float4*)(arow_f + kc + skc + 8);
            float4 u3 = *(const float4*)(arow_f + kc + skc + 12);
            unsigned short tmp[16] __attribute__((aligned(16)));
            tmp[0] = f2bf(u0.x); tmp[1] = f2bf(u0.y); tmp[2]  = f2bf(u0.z); tmp[3]  = f2bf(u0.w);
            tmp[4] = f2bf(u1.x); tmp[5] = f2bf(u1.y); tmp[6]  = f2bf(u1.z); tmp[7]  = f2bf(u1.w);
            tmp[8] = f2bf(u2.x); tmp[9] = f2bf(u2.y); tmp[10] = f2bf(u2.z); tmp[11] = f2bf(u2.w);
            tmp[12] = f2bf(u3.x); tmp[13] = f2bf(u3.y); tmp[14] = f2bf(u3.z); tmp[15] = f2bf(u3.w);
            *(uint4*)&Asm[srow * 40 + skc]     = *(const uint4*)tmp;
            *(uint4*)&Asm[srow * 40 + skc + 8] = *(const uint4*)(tmp + 8);
        } else {
            *(uint4*)&Asm[srow * 40 + skc]     = *(const uint4*)(arow_h + kc + skc);
            *(uint4*)&Asm[srow * 40 + skc + 8] = *(const uint4*)(arow_h + kc + skc + 8);
        }
        if (csrc) {
            unsigned short tmp[16] __attribute__((aligned(16)));
            int n_abs = tile_n + srow;
            #pragma unroll
            for (int j = 0; j < 16; j++) {
                int k_abs = kc + skc + j;
                tmp[j] = f2bf(csrc[(k_abs - n_abs) & 511]);
            }
            *(uint4*)&Bsm[srow * 40 + skc]     = *(const uint4*)tmp;
            *(uint4*)&Bsm[srow * 40 + skc + 8] = *(const uint4*)(tmp + 8);
        } else {
            *(uint4*)&Bsm[srow * 40 + skc]     = *(const uint4*)(brow_h + kc + skc);
            *(uint4*)&Bsm[srow * 40 + skc + 8] = *(const uint4*)(brow_h + kc + skc + 8);
        }
        __syncthreads();
        bf16x8 av[4], bv[4];
        #pragma unroll
        for (int mi = 0; mi < 4; mi++)
            av[mi] = *(const bf16x8*)&Asm[(wm + mi * 16 + fr) * 40 + fq];
        #pragma unroll
        for (int ni = 0; ni < 4; ni++)
            bv[ni] = *(const bf16x8*)&Bsm[(wn + ni * 16 + fr) * 40 + fq];
        #pragma unroll
        for (int mi = 0; mi < 4; mi++)
            #pragma unroll
            for (int ni = 0; ni < 4; ni++)
                acc[mi][ni] = __builtin_amdgcn_mfma_f32_16x16x32_bf16(
                    av[mi], bv[ni], acc[mi][ni], 0, 0, 0);
    }

    #pragma unroll
    for (int mi = 0; mi < 4; mi++) {
        #pragma unroll
        for (int ni = 0; ni < 4; ni++) {
            #pragma unroll
            for (int rg = 0; rg < 4; rg++) {
                int row = tile_m + wm + mi * 16 + (lane >> 4) * 4 + rg;
                int col = tile_n + wn + ni * 16 + (lane & 15);
                float v = acc[mi][ni][rg];
                if (bias) v += bias[col];
                if (act == 1) v = fast_tanh(v);
                long oidx = (long)bz * out_bstride + (long)row * N + col;
                if (outb) outb[oidx] = f2bf(v);
                else outf[oidx] = v;
            }
        }
    }
}

// ---------------------------------------------------------------------------
// lstm_g1: fused G1 GEMM + persistent LSTM recurrence. 2112 blocks x 512.
//   blocks 0..63   : LSTM, R12-exact partition (cq=bid&7 clique->XCD), plus
//                    Zx sentinel poll (grouped reload, s_sleep(2) in loop).
//   blocks 64..2111: G1 tile (128x128 of Zx = Ebf @ W_ih^T + b), 8 waves x
//                    64x32 sub-tiles, t-MAJOR tile order, dword-packed
//                    relaxed-agent atomic publishes.
// ---------------------------------------------------------------------------
#define WSTRIDE 520
#define ZL(g,r,d) zl[((g)*8+(r))*65+(d)]

__global__ __launch_bounds__(512, 2)
void lstm_g1(const float* __restrict__ Whh,
             unsigned int* __restrict__ Zxu,      // Zx bf16 as dwords
             unsigned int* __restrict__ Hsu,      // Hs bf16 as dwords
             const void* __restrict__ Abase, int a_f32,
             const int* __restrict__ xg,
             const unsigned short* __restrict__ Wih_bf,
             const float* __restrict__ b_lstm)
{
    __shared__ __align__(16) char smem[25088];
    const int tid = threadIdx.x;
    const int lane = tid & 63;
    const int w = tid >> 6;
    const int fr = lane & 15;
    const int fq = (lane >> 4) * 8;
    f32x4 zero4 = {0.f, 0.f, 0.f, 0.f};

    if (blockIdx.x >= 64) {
        // ================= G1 region =================
        unsigned short* Asm = (unsigned short*)smem;            // 128*40
        unsigned short* Bsm = (unsigned short*)(smem + 10240);  // 128*40

        const int gb = (int)blockIdx.x - 64;
        const int bx = gb & 15;
        const int y  = gb >> 4;          // 0..127
        const int b  = y & 63;           // batch  (t-major: all tb=0 first)
        const int tb = y >> 6;           // 0 or 1
        const int tile_m = b * 256 + tb * 128;
        const int tile_n = bx * 128;

        const int srow = tid >> 2;        // 0..127
        const int skc = (tid & 3) * 8;    // 0,8,16,24

        const float* arow_f = nullptr;
        const unsigned short* arow_h = nullptr;
        if (a_f32) arow_f = (const float*)Abase + (long)xg[tile_m + srow] * 512;
        else       arow_h = (const unsigned short*)Abase + (long)(tile_m + srow) * 512;
        const unsigned short* brow_h = Wih_bf + (long)(tile_n + srow) * 512;

        const int wm = (w >> 2) * 64;     // 0 or 64
        const int wn = (w & 3) * 32;      // 0,32,64,96

        f32x4 acc[4][2];
        #pragma unroll
        for (int mi = 0; mi < 4; mi++) { acc[mi][0] = zero4; acc[mi][1] = zero4; }

        for (int kc = 0; kc < 512; kc += 32) {
            __syncthreads();
            if (a_f32) {
                float4 u0 = *(const float4*)(arow_f + kc + skc);
                float4 u1 = *(const float4*)(arow_f + kc + skc + 4);
                unsigned short tmp[8] __attribute__((aligned(16)));
                tmp[0] = f2bf(u0.x); tmp[1] = f2bf(u0.y); tmp[2] = f2bf(u0.z); tmp[3] = f2bf(u0.w);
                tmp[4] = f2bf(u1.x); tmp[5] = f2bf(u1.y); tmp[6] = f2bf(u1.z); tmp[7] = f2bf(u1.w);
                *(uint4*)&Asm[srow * 40 + skc] = *(const uint4*)tmp;
            } else {
                *(uint4*)&Asm[srow * 40 + skc] = *(const uint4*)(arow_h + kc + skc);
            }
            *(uint4*)&Bsm[srow * 40 + skc] = *(const uint4*)(brow_h + kc + skc);
            __syncthreads();
            bf16x8 av[4], bv[2];
            #pragma unroll
            for (int mi = 0; mi < 4; mi++)
                av[mi] = *(const bf16x8*)&Asm[(wm + mi * 16 + fr) * 40 + fq];
            #pragma unroll
            for (int ni = 0; ni < 2; ni++)
                bv[ni] = *(const bf16x8*)&Bsm[(wn + ni * 16 + fr) * 40 + fq];
            #pragma unroll
            for (int mi = 0; mi < 4; mi++)
                #pragma unroll
                for (int ni = 0; ni < 2; ni++)
                    acc[mi][ni] = __builtin_amdgcn_mfma_f32_16x16x32_bf16(
                        av[mi], bv[ni], acc[mi][ni], 0, 0, 0);
        }

        // publish: pack lane-pairs into dwords, relaxed-agent atomic store
        #pragma unroll
        for (int mi = 0; mi < 4; mi++) {
            #pragma unroll
            for (int ni = 0; ni < 2; ni++) {
                #pragma unroll
                for (int rg = 0; rg < 4; rg++) {
                    int row = tile_m + wm + mi * 16 + (lane >> 4) * 4 + rg;
                    int col = tile_n + wn + ni * 16 + (lane & 15);
                    float v = acc[mi][ni][rg] + b_lstm[col];
                    float vx = __shfl_xor(v, 1);
                    if (!(lane & 1)) {
                        unsigned pk = (unsigned)f2bf(v) | ((unsigned)f2bf(vx) << 16);
                        __hip_atomic_store(Zxu + (((long)row * 2048 + col) >> 1), pk,
                                           __ATOMIC_RELAXED, __HIP_MEMORY_SCOPE_AGENT);
                    }
                }
            }
        }
        return;
    }

    // ================= LSTM region (R12-exact + Zx poll) =================
    unsigned short* hsm = (unsigned short*)smem;            // 16*520 ushorts
    float* zl = (float*)(smem + 16640);                     // 4*8*65 floats

    const int cq  = blockIdx.x & 7;
    const int nbp = blockIdx.x >> 3;
    const int g = w >> 1;
    const int f = w & 1;

    bf16x8 wfrag[2][16];
    #pragma unroll
    for (int n = 0; n < 2; n++) {
        const float* wrow = Whh + (long)(g * 512 + nbp * 64 + f * 32 + n * 16 + fr) * 512;
        #pragma unroll
        for (int c = 0; c < 16; c++) {
            int k0 = c * 32 + fq;
            float4 u0 = *(const float4*)(wrow + k0);
            float4 u1 = *(const float4*)(wrow + k0 + 4);
            unsigned short tmp[8] __attribute__((aligned(16)));
            tmp[0] = f2bf(u0.x); tmp[1] = f2bf(u0.y); tmp[2] = f2bf(u0.z); tmp[3] = f2bf(u0.w);
            tmp[4] = f2bf(u1.x); tmp[5] = f2bf(u1.y); tmp[6] = f2bf(u1.z); tmp[7] = f2bf(u1.w);
            wfrag[n][c] = *(const bf16x8*)tmp;
        }
    }

    for (int i = tid; i < 16 * WSTRIDE / 2; i += 512)
        ((unsigned*)hsm)[i] = 0;

    int st_r[4], st_dp[4];
    #pragma unroll
    for (int k = 0; k < 4; k++) {
        int idx = k * 512 + tid;
        st_r[k] = idx >> 8;
        st_dp[k] = idx & 255;
    }

    const int grow = (tid & 255) >> 5;
    const int d0 = (tid & 31) * 2;
    const int b_own = cq * 8 + grow;
    const int dg = nbp * 64 + d0;
    float ca = 0.f, cb = 0.f;

    for (int t = 0; t < T_; t++) {
        // Zx gate pre-activations: sentinel-poll (G1 may still be writing)
        unsigned zi_u = 0, zf_u = 0, zg_u = 0, zo_u = 0;
        if (tid < 256) {
            const long zd = (((long)b_own * T_ + t) * H4 + dg) >> 1;
            zi_u = ald(Zxu + zd + 0 * 256);
            zf_u = ald(Zxu + zd + 1 * 256);
            zg_u = ald(Zxu + zd + 2 * 256);
            zo_u = ald(Zxu + zd + 3 * 256);
            while (true) {
                bool pend = (zi_u == SENT) | (zf_u == SENT) |
                            (zg_u == SENT) | (zo_u == SENT);
                if (!__ballot(pend)) break;
                __builtin_amdgcn_s_sleep(2);
                zi_u = ald(Zxu + zd + 0 * 256);
                zf_u = ald(Zxu + zd + 1 * 256);
                zg_u = ald(Zxu + zd + 2 * 256);
                zo_u = ald(Zxu + zd + 3 * 256);
            }
        }

        f32x4 an0 = zero4, an1 = zero4;
        if (t > 0) {
            unsigned vv[4];
            long ad[4];
            #pragma unroll
            for (int k = 0; k < 4; k++) {
                ad[k] = ((long)(cq * 8 + st_r[k]) * T_ + (t - 1)) * 256 + st_dp[k];
                vv[k] = ald(Hsu + ad[k]);
            }
            while (true) {
                bool pend = false;
                #pragma unroll
                for (int k = 0; k < 4; k++) pend |= (vv[k] == SENT);
                if (!__ballot(pend)) break;
                #pragma unroll
                for (int k = 0; k < 4; k++) vv[k] = ald(Hsu + ad[k]);
            }
            #pragma unroll
            for (int k = 0; k < 4; k++) {
                *(unsigned*)&hsm[st_r[k] * WSTRIDE + st_dp[k] * 2] = vv[k];
            }
            __syncthreads();   // S1
            const unsigned short* arow = hsm + fr * WSTRIDE;
            f32x4 a0[4] = {zero4, zero4, zero4, zero4};
            f32x4 a1[4] = {zero4, zero4, zero4, zero4};
            #pragma unroll
            for (int c = 0; c < 16; c += 4) {
                bf16x8 x0 = *(const bf16x8*)(arow + (c + 0) * 32 + fq);
                bf16x8 x1 = *(const bf16x8*)(arow + (c + 1) * 32 + fq);
                bf16x8 x2 = *(const bf16x8*)(arow + (c + 2) * 32 + fq);
                bf16x8 x3 = *(const bf16x8*)(arow + (c + 3) * 32 + fq);
                a0[0] = __builtin_amdgcn_mfma_f32_16x16x32_bf16(x0, wfrag[0][c + 0], a0[0], 0, 0, 0);
                a0[1] = __builtin_amdgcn_mfma_f32_16x16x32_bf16(x1, wfrag[0][c + 1], a0[1], 0, 0, 0);
                a0[2] = __builtin_amdgcn_mfma_f32_16x16x32_bf16(x2, wfrag[0][c + 2], a0[2], 0, 0, 0);
                a0[3] = __builtin_amdgcn_mfma_f32_16x16x32_bf16(x3, wfrag[0][c + 3], a0[3], 0, 0, 0);
                a1[0] = __builtin_amdgcn_mfma_f32_16x16x32_bf16(x0, wfrag[1][c + 0], a1[0], 0, 0, 0);
                a1[1] = __builtin_amdgcn_mfma_f32_16x16x32_bf16(x1, wfrag[1][c + 1], a1[1], 0, 0, 0);
                a1[2] = __builtin_amdgcn_mfma_f32_16x16x32_bf16(x2, wfrag[1][c + 2], a1[2], 0, 0, 0);
                a1[3] = __builtin_amdgcn_mfma_f32_16x16x32_bf16(x3, wfrag[1][c + 3], a1[3], 0, 0, 0);
            }
            an0 = (a0[0] + a0[1]) + (a0[2] + a0[3]);
            an1 = (a1[0] + a1[1]) + (a1[2] + a1[3]);
        }
        if (lane < 32) {
            const int rb = (lane >> 4) * 4;
            const int cl = f * 32 + (lane & 15);
            #pragma unroll
            for (int rg = 0; rg < 4; rg++) {
                ZL(g, rb + rg, cl)      = an0[rg];
                ZL(g, rb + rg, cl + 16) = an1[rg];
            }
        }
        __syncthreads();       // S2
        if (tid < 256) {
            float zi0 = ZL(0, grow, d0)     + bf2f_lo(zi_u);
            float zi1 = ZL(0, grow, d0 + 1) + bf2f_hi(zi_u);
            float zf0 = ZL(1, grow, d0)     + bf2f_lo(zf_u);
            float zf1 = ZL(1, grow, d0 + 1) + bf2f_hi(zf_u);
            float zg0 = ZL(2, grow, d0)     + bf2f_lo(zg_u);
            float zg1 = ZL(2, grow, d0 + 1) + bf2f_hi(zg_u);
            float zo0 = ZL(3, grow, d0)     + bf2f_lo(zo_u);
            float zo1 = ZL(3, grow, d0 + 1) + bf2f_hi(zo_u);

            ca = fast_sigmoid(zf0) * ca + fast_sigmoid(zi0) * fast_tanh(zg0);
            cb = fast_sigmoid(zf1) * cb + fast_sigmoid(zi1) * fast_tanh(zg1);
            float h0 = fast_sigmoid(zo0) * fast_tanh(ca);
            float h1 = fast_sigmoid(zo1) * fast_tanh(cb);

            unsigned hp = (unsigned)f2bf(h0) | ((unsigned)f2bf(h1) << 16);
            __hip_atomic_store(Hsu + ((long)b_own * T_ + t) * 256 + nbp * 32 + (tid & 31),
                               hp, __ATOMIC_RELAXED, __HIP_MEMORY_SCOPE_AGENT);
        }
    }
}

// ---------------------------------------------------------------------------
// tail_kernel: fused attn_r + hstar + out (unchanged from R17)
// ---------------------------------------------------------------------------
__global__ __launch_bounds__(256)
void tail_kernel(const float* __restrict__ apre,
                 const unsigned short* __restrict__ Hs,
                 const float* __restrict__ w_p,
                 const float* __restrict__ w_x,
                 const float* __restrict__ w_f,
                 const float* __restrict__ b_f,
                 float* __restrict__ out)
{
    __shared__ __align__(16) float apc[16 * 512];
    __shared__ __align__(16) unsigned short hc[16 * 512];
    __shared__ float rs[512];
    __shared__ float hts[512];
    __shared__ float hsr[512];
    __shared__ float lg[512];
    __shared__ float red[8];

    const int b = blockIdx.x, tid = threadIdx.x;
    const int d1 = tid + 256;
    const float* apb = apre + (long)b * T_ * D_;
    const unsigned short* hpb = Hs + (long)b * T_ * D_;

    float mx0 = -3.0e38f, sm0 = 0.f, ac0 = 0.f;
    float mx1 = -3.0e38f, sm1 = 0.f, ac1 = 0.f;

    for (int t0 = 0; t0 < T_; t0 += 16) {
        __syncthreads();
        for (int idx = tid; idx < 16 * 128; idx += 256) {
            int rr = idx >> 7, cc = (idx & 127) * 4;
            *(float4*)&apc[rr * 512 + cc] = *(const float4*)(apb + (long)(t0 + rr) * 512 + cc);
        }
        for (int idx = tid; idx < 16 * 64; idx += 256) {
            int rr = idx >> 6, cc = (idx & 63) * 8;
            *(uint4*)&hc[rr * 512 + cc] = *(const uint4*)(hpb + (long)(t0 + rr) * 512 + cc);
        }
        __syncthreads();
        #pragma unroll
        for (int i = 0; i < 16; i++) {
            float v0 = apc[i * 512 + tid];
            float h0 = bf2f(hc[i * 512 + tid]);
            if (v0 > mx0) {
                float fct = __expf(mx0 - v0);
                sm0 = sm0 * fct + 1.f;
                ac0 = ac0 * fct + h0;
                mx0 = v0;
            } else {
                float e = __expf(v0 - mx0);
                sm0 += e;
                ac0 += e * h0;
            }
            float v1 = apc[i * 512 + d1];
            float h1 = bf2f(hc[i * 512 + d1]);
            if (v1 > mx1) {
                float fct = __expf(mx1 - v1);
                sm1 = sm1 * fct + 1.f;
                ac1 = ac1 * fct + h1;
                mx1 = v1;
            } else {
                float e = __expf(v1 - mx1);
                sm1 += e;
                ac1 += e * h1;
            }
        }
    }
    rs[tid] = ac0 / sm0;
    rs[d1]  = ac1 / sm1;
    const long hlast = ((long)b * T_ + (T_ - 1)) * D_;
    hts[tid] = bf2f(Hs[hlast + tid]);
    hts[d1]  = bf2f(Hs[hlast + d1]);
    __syncthreads();

    for (int d = tid; d < 512; d += 256) {
        const float* wp = w_p + (long)d * D_;
        const float* wx = w_x + (long)d * D_;
        float acc = 0.f;
        for (int e = 0; e < 512; e += 4) {
            float4 p1 = *(const float4*)(wp + e);
            float4 p2 = *(const float4*)(wx + e);
            acc += p1.x * rs[e] + p1.y * rs[e + 1] + p1.z * rs[e + 2] + p1.w * rs[e + 3];
            acc += p2.x * hts[e] + p2.y * hts[e + 1] + p2.z * hts[e + 2] + p2.w * hts[e + 3];
        }
        hsr[d] = fast_tanh(acc);
    }
    __syncthreads();

    for (int d = tid; d < 512; d += 256) {
        const float* wr = w_f + (long)d * D_;
        float acc = b_f[d];
        for (int e = 0; e < 512; e += 4) {
            float4 p = *(const float4*)(wr + e);
            acc += p.x * hsr[e] + p.y * hsr[e + 1] + p.z * hsr[e + 2] + p.w * hsr[e + 3];
        }
        lg[d] = acc;
    }
    __syncthreads();
    float m0 = fmaxf(lg[tid], lg[d1]);
    for (int off = 32; off > 0; off >>= 1) m0 = fmaxf(m0, __shfl_down(m0, off, 64));
    if ((tid & 63) == 0) red[tid >> 6] = m0;
    __syncthreads();
    float bmax = fmaxf(fmaxf(red[0], red[1]), fmaxf(red[2], red[3]));
    float e0 = __expf(lg[tid] - bmax);
    float e1 = __expf(lg[d1] - bmax);
    float s0 = e0 + e1;
    for (int off = 32; off > 0; off >>= 1) s0 += __shfl_down(s0, off, 64);
    if ((tid & 63) == 0) red[4 + (tid >> 6)] = s0;
    __syncthreads();
    float inv = 1.f / (red[4] + red[5] + red[6] + red[7]);
    out[b * D_ + tid] = e0 * inv;
    out[b * D_ + d1]  = e1 * inv;
}

// ---------------------------------------------------------------------------
extern "C" void kernel_launch(void* const* d_in, const int* in_sizes, int n_in,
                              void* d_out, int out_size, void* d_ws, size_t ws_size,
                              hipStream_t stream)
{
    (void)in_sizes; (void)n_in; (void)out_size;

    const int* x = (const int*)d_in[0];
    const int* s = (const int*)d_in[1];
    const float* embed  = (const float*)d_in[2];
    const float* W_ih   = (const float*)d_in[3];
    const float* W_hh   = (const float*)d_in[4];
    const float* b_lstm = (const float*)d_in[5];
    const float* w_y = (const float*)d_in[6];
    const float* w_t = (const float*)d_in[7];
    const float* w_p = (const float*)d_in[8];
    const float* w_x = (const float*)d_in[9];
    const float* w_f = (const float*)d_in[10];
    const float* b_f = (const float*)d_in[11];

    // Workspace (overlaid):
    //   [0,64MiB)   phase1: Zx bf16 [16384][2048] (sentinel-filled exchange)
    //               phase2: apre f32 @0, mbuf bf16 @32MiB, Ybuf bf16 @48MiB
    //   [64MiB,+16MiB) Hs bf16 (exchange; sentinel-filled)
    //   @86114304: s_norm
    //   @86507520: Wcat_bf = bf16 [W_ih | w_y | w_t]  (3 MiB)
    //   @89653248: Ebf bf16 [16384][512] (16 MiB) -- only if ws_size allows
    char* ws = (char*)d_ws;
    unsigned short* Zx   = (unsigned short*)(ws + 0);
    float*          apre = (float*)(ws + 0);
    unsigned short* mbuf = (unsigned short*)(ws + 33554432);
    unsigned short* Ybuf = (unsigned short*)(ws + 50331648);
    unsigned short* Hs   = (unsigned short*)(ws + 67108864);
    float* s_norm = (float*)(ws + 86114304);
    unsigned short* Wcat = (unsigned short*)(ws + 86507520);
    unsigned short* Wih_bf = Wcat;
    unsigned short* wy_bf  = Wcat + 1048576;
    unsigned short* wt_bf  = Wcat + 1310720;
    unsigned short* Ebf  = (unsigned short*)(ws + 89653248);
    const int use_ebf = (ws_size >= (size_t)89653248 + 16777216u);

    // 0) fused prep: Hs fill | weight conv | embed gather-conv | aspect norm
    //    | Zx sentinel fill. One launch, 15874 blocks.
    prep_kernel<<<dim3(15874), dim3(256), 0, stream>>>(
        x, s, embed, W_ih, w_y, w_t, Wcat, Ebf, (uint4*)Hs, (uint4*)Zx,
        s_norm, use_ebf);

    // 1) fused G1 + recurrence: blocks 0-63 LSTM, 64-2111 G1 (t-major).
    if (use_ebf)
        lstm_g1<<<dim3(2112), dim3(512), 0, stream>>>(
            W_hh, (unsigned int*)Zx, (unsigned int*)Hs,
            Ebf, 0, x, Wih_bf, b_lstm);
    else
        lstm_g1<<<dim3(2112), dim3(512), 0, stream>>>(
            W_hh, (unsigned int*)Zx, (unsigned int*)Hs,
            embed, 1, x, Wih_bf, b_lstm);

    // ---- phase 2: Zx dead; region reused for apre/mbuf/Ybuf ----

    // 2) G2: m[b] = Hs[b] @ circ(s_norm[b])^T  (M=256, N=512, K=512, 64 batches)
    gemm_bt<<<dim3(4, 2, 64), dim3(256), 0, stream>>>(
        Hs, 0, nullptr, nullptr, s_norm, nullptr, mbuf, nullptr,
        512, 512, (long)(T_ * D_), (long)(T_ * D_), 0);

    // 3) G3: Y = tanh(m @ w_y^T)  (M=16384, N=512, K=512)
    gemm_bt<<<dim3(4, 128, 1), dim3(256), 0, stream>>>(
        mbuf, 0, nullptr, wy_bf, nullptr, nullptr, Ybuf, nullptr,
        512, 512, 0L, 0L, 1);

    // 4) G4: apre = Y @ w_t^T
    gemm_bt<<<dim3(4, 128, 1), dim3(256), 0, stream>>>(
        Ybuf, 0, nullptr, wt_bf, nullptr, nullptr, nullptr, apre,
        512, 512, 0L, 0L, 0);

    // 5) fused tail: online softmax+r, h_star, logits+softmax (1 block/batch)
    tail_kernel<<<dim3(64), dim3(256), 0, stream>>>(
        apre, Hs, w_p, w_x, w_f, b_f, (float*)d_out);
}